// Round 8
// baseline (316.184 us; speedup 1.0000x reference)
//
#include <hip/hip_runtime.h>
#include <hip/hip_bf16.h>

// LinkPredictorGAT: out[e] = relu(concat(z[src[e]], z[dst[e]]) @ W1 + b1) @ W2 + b2
// R16: gemm rebuilt as STAGE-ONCE / ZERO-BARRIER persistent kernel (gemm_hp).
// Evidence chain: R14 (0 barriers, L2-direct B) 99.7us = operand latency;
// R12 (4 barriers) 68us; R15 (8 barriers, 2x occupancy) 78us -> each in-loop
// stage->vmcnt(0)->barrier cycle costs ~2.5us and occupancy does NOT fix it.
// Fix: one H-half's full-K B image = exactly 64 KB = max static LDS. Block (256thr,
// 4 waves) owns half hf=blockIdx&1, stages it ONCE (16 gl_lds16/thread + single
// __syncthreads), then grid-strides over 128-row tiles with NO barriers: wave =
// 32 rows x 128 cols (mf=2, nf=8, acc=64 regs), depth-4 rolling A prefetch.
// Grid 512 = 2 blocks/CU exactly (persistent). z read twice (once/half); 2nd read
// L3-served (100MB < 256MB). Numerics bit-identical to R11/R12 (same image, RNE).
// edge_out: unchanged (gather-bound floor; R12 VALU-halving test proved it).

typedef __attribute__((ext_vector_type(4))) float floatx4;
typedef __attribute__((ext_vector_type(8))) short short8;
typedef _Float16 half8v __attribute__((ext_vector_type(8)));
typedef __fp16 fp16x2 __attribute__((ext_vector_type(2)));

#if defined(__has_builtin)
#if __has_builtin(__builtin_amdgcn_fdot2)
#define HAVE_FDOT2 1
#endif
#endif

__device__ __forceinline__ unsigned short bf16rne(float x) {
    unsigned int u = __float_as_uint(x);
    u += 0x7fffu + ((u >> 16) & 1u);
    return (unsigned short)(u >> 16);
}

// async global->LDS, 16 B per lane; LDS dest = wave-uniform base + lane*16.
__device__ __forceinline__ void gl_lds16(const void* g, void* l) {
    __builtin_amdgcn_global_load_lds(
        (const __attribute__((address_space(1))) void*)(unsigned long long)g,
        (__attribute__((address_space(3))) void*)(unsigned)(unsigned long long)l,
        16, 0, 0);
}

// ---- W1 [512][128] fp32 -> BTc2: two per-half swizzled linear images ----
// Per half (k_local in [0,256)): L(s,n,g',j) = s*4096 + n*32 + g'*8 + j shorts;
// s = k_local>>5, g = (k_local>>3)&3, j = k_local&7, g' = g ^ ((n>>1)&3).
// Half h occupies shorts [h*32768, +32768). Reader: 0 bank conflicts (verified).
__global__ void cvt_w1h(const float* __restrict__ W1, unsigned short* __restrict__ BTc2) {
    int t = blockIdx.x * blockDim.x + threadIdx.x;   // 0..65535
    int hf = t >> 15, rem = t & 32767;
    int s = rem >> 12, rem2 = rem & 4095;
    int n = rem2 >> 5, rem3 = rem2 & 31;
    int gp = rem3 >> 3, j = rem3 & 7;
    int g = gp ^ ((n >> 1) & 3);
    int k = hf * 256 + s * 32 + g * 8 + j;
    BTc2[t] = bf16rne(W1[k * 128 + n]);
}

// ---- old-path W1 image (512 rows), kept for the low-workspace fallback ----
__global__ void cvt_w1(const float* __restrict__ W1, unsigned short* __restrict__ BTc) {
    int t = blockIdx.x * blockDim.x + threadIdx.x;   // 0..65535
    int s = t >> 12, rem = t & 4095;
    int n = rem >> 5, rem2 = rem & 31;
    int gp = rem2 >> 3, j = rem2 & 7;
    int g = gp ^ ((n >> 1) & 3);
    int k = s * 32 + g * 8 + j;
    BTc[t] = bf16rne(W1[k * 128 + n]);
}

// ---- precompute GEMM: stage-once, zero-barrier persistent ----
// H[row][hf*128 + c] = z[row] @ W1[hf*256: , c]  (+b1 if hf==0), fp16 out.
// Block: 256 thr / 4 waves, owns half hf = blockIdx&1; LDS = that half's full
// 64 KB image. Tile loop: wave = 32 rows x 128 cols; block = 128 rows/tile.
__global__ __launch_bounds__(256, 2)
void gemm_hp(const float* __restrict__ zf, int nnodes,
             const unsigned short* __restrict__ BTc2,
             const float* __restrict__ b1, _Float16* __restrict__ Hh)
{
    __shared__ unsigned short B[32768];               // 64 KB: one half, full K=256

    const int t = threadIdx.x;
    const int wid = t >> 6;
    const int lane = t & 63;
    const int l15 = lane & 15;
    const int quad = lane >> 4;
    const int hf = blockIdx.x & 1;
    const int b2 = blockIdx.x >> 1;                   // 0..255: row-tile stream id
    const int ntiles = (nnodes + 127) >> 7;           // 128 rows per block-tile

    // ---- stage the half image ONCE (only barrier in the kernel) ----
    {
        const char* g = (const char*)(BTc2 + hf * 32768) + t * 16;
        char* l = (char*)B + t * 16;
#pragma unroll
        for (int i = 0; i < 16; ++i)
            gl_lds16(g + i * 4096, l + i * 4096);
    }
    __syncthreads();                                  // compiler emits vmcnt(0) drain

    // reader base (swizzled; 0 bank conflicts — same pattern as R11/R12)
    const int swz = (l15 >> 1) & 3;
    const unsigned short* bbase = B + l15 * 32 + (quad ^ swz) * 8;

    float b1v[8];
#pragma unroll
    for (int nf = 0; nf < 8; ++nf)
        b1v[nf] = (hf == 0) ? b1[nf * 16 + l15] : 0.f;

    const char* zbb = (const char*)zf;

    for (int tile = b2; tile < ntiles; tile += 256) {
        const int m0 = tile * 128 + wid * 32;

        unsigned offs[2];
#pragma unroll
        for (int mf = 0; mf < 2; ++mf) {
            int r = m0 + mf * 16 + l15;
            r = r < nnodes ? r : nnodes - 1;          // clamp (stores masked)
            offs[mf] = (unsigned)r * 1024u;           // fp32 row = 1024 B
        }

        // A loader: K-step ks in [0,8); fp32 -> bf16 in-register (RNE)
        auto load_a = [&](int ks, short8* dst) {
            const int cb = ks * 128 + quad * 32;
#pragma unroll
            for (int mf = 0; mf < 2; ++mf) {
                const float* pf = (const float*)(zbb + (size_t)offs[mf] + cb);
                float4 f0 = *(const float4*)pf;
                float4 f1 = *(const float4*)(pf + 4);
                short8 av;
                av[0] = (short)bf16rne(f0.x); av[1] = (short)bf16rne(f0.y);
                av[2] = (short)bf16rne(f0.z); av[3] = (short)bf16rne(f0.w);
                av[4] = (short)bf16rne(f1.x); av[5] = (short)bf16rne(f1.y);
                av[6] = (short)bf16rne(f1.z); av[7] = (short)bf16rne(f1.w);
                dst[mf] = av;
            }
        };

        floatx4 acc[2][8];
#pragma unroll
        for (int mf = 0; mf < 2; ++mf)
#pragma unroll
            for (int nf = 0; nf < 8; ++nf)
                acc[mf][nf] = (floatx4){0.f, 0.f, 0.f, 0.f};

        short8 A[4][2];                               // depth-4 rolling A prefetch
        load_a(0, A[0]);
        load_a(1, A[1]);
        load_a(2, A[2]);

#pragma unroll
        for (int ks = 0; ks < 8; ++ks) {              // K=256, no barriers
            if (ks + 3 < 8) load_a(ks + 3, A[(ks + 3) & 3]);

            const unsigned short* bs = bbase + ks * 4096;
            const short8* ac = A[ks & 3];

            short8 bfr[4];
#pragma unroll
            for (int nf = 0; nf < 4; ++nf)
                bfr[nf] = *(const short8*)(bs + nf * 512);
#pragma unroll
            for (int nf = 0; nf < 4; ++nf)
#pragma unroll
                for (int mf = 0; mf < 2; ++mf)
                    acc[mf][nf] = __builtin_amdgcn_mfma_f32_16x16x32_bf16(
                        ac[mf], bfr[nf], acc[mf][nf], 0, 0, 0);
#pragma unroll
            for (int nf = 0; nf < 4; ++nf)
                bfr[nf] = *(const short8*)(bs + (nf + 4) * 512);
#pragma unroll
            for (int nf = 0; nf < 4; ++nf)
#pragma unroll
                for (int mf = 0; mf < 2; ++mf)
                    acc[mf][nf + 4] = __builtin_amdgcn_mfma_f32_16x16x32_bf16(
                        ac[mf], bfr[nf], acc[mf][nf + 4], 0, 0, 0);
        }

        // epilogue: col = l15 + 16*nf (within own half); row = quad*4 + r (+16mf)
#pragma unroll
        for (int mf = 0; mf < 2; ++mf) {
#pragma unroll
            for (int r = 0; r < 4; ++r) {
                int row = m0 + mf * 16 + quad * 4 + r;
                if (row < nnodes) {
                    _Float16* hp = Hh + (size_t)row * 256 + hf * 128 + l15;
#pragma unroll
                    for (int nf = 0; nf < 8; ++nf)
                        hp[nf * 16] = (_Float16)(acc[mf][nf][r] + b1v[nf]);
                }
            }
        }
    }
}

// ---- edge phase: pure gather + packed-fp16 relu-dot (unchanged; gather-bound) ----
// 16 lanes/edge, 4 edges per thread-slot; block = 256 thr covers 64 edges.
__global__ __launch_bounds__(256)
void edge_out(const _Float16* __restrict__ Hh, const int* __restrict__ eli,
              int E, int nnodes,
              const float* __restrict__ W2, const float* __restrict__ b2,
              float* __restrict__ out)
{
    const int t = threadIdx.x;
    const int lane = t & 63;
    const int wid = t >> 6;
    const int l15 = lane & 15;
    const int grp = lane >> 4;

    fp16x2 w2h[4];
#pragma unroll
    for (int p = 0; p < 4; ++p) {
        w2h[p][0] = (__fp16)W2[l15 * 8 + 2 * p];
        w2h[p][1] = (__fp16)W2[l15 * 8 + 2 * p + 1];
    }
    const float b2s = b2[0];

    const int e0 = blockIdx.x * 64 + wid * 16 + grp;

    half8v hs[4], hd[4];
    int ee[4];
#pragma unroll
    for (int i = 0; i < 4; ++i) {
        int e = e0 + i * 4;
        ee[i] = e;
        int ec = e < E ? e : E - 1;
        int s = eli[ec];
        int d = eli[E + ec];
        s = s < 0 ? 0 : (s >= nnodes ? nnodes - 1 : s);
        d = d < 0 ? 0 : (d >= nnodes ? nnodes - 1 : d);
        hs[i] = *(const half8v*)(Hh + (size_t)s * 256 + l15 * 8);
        hd[i] = *(const half8v*)(Hh + (size_t)d * 256 + 128 + l15 * 8);
    }
    const half8v zero = {};
#pragma unroll
    for (int i = 0; i < 4; ++i) {
        half8v v = hs[i] + hd[i];                         // v_pk_add_f16 x4
        v = __builtin_elementwise_max(v, zero);           // v_pk_max_f16 x4
        float sacc = 0.f;
#if defined(HAVE_FDOT2)
#pragma unroll
        for (int p = 0; p < 4; ++p) {
            fp16x2 a;
            a[0] = (__fp16)v[2 * p];
            a[1] = (__fp16)v[2 * p + 1];
            sacc = __builtin_amdgcn_fdot2(a, w2h[p], sacc, false);  // v_dot2_f32_f16
        }
#else
#pragma unroll
        for (int p = 0; p < 4; ++p) {
            sacc = fmaf((float)v[2 * p],     (float)w2h[p][0], sacc);
            sacc = fmaf((float)v[2 * p + 1], (float)w2h[p][1], sacc);
        }
#endif
        sacc += __shfl_xor(sacc, 1);
        sacc += __shfl_xor(sacc, 2);
        sacc += __shfl_xor(sacc, 4);
        sacc += __shfl_xor(sacc, 8);
        if (l15 == 0 && ee[i] < E)
            out[ee[i]] = sacc + b2s;
    }
}

// ---- R8 fused kernel (fp32-A variant), kept for the low-workspace fallback ----
__global__ __launch_bounds__(256, 2)
void fused_mlp_f32(const float* __restrict__ zf, const int* __restrict__ eli,
                   int E, int nnodes,
                   const unsigned short* __restrict__ BTc,
                   const float* __restrict__ b1, const float* __restrict__ W2,
                   const float* __restrict__ b2, float* __restrict__ out)
{
    __shared__ unsigned short btile[2][4][128][32];

    const int t = threadIdx.x;
    const int wid = t >> 6;
    const int lane = t & 63;
    const int l15 = lane & 15;
    const int quad = lane >> 4;
    const int m0 = blockIdx.x * 256 + wid * 64;

    unsigned offs[4], offd[4];
#pragma unroll
    for (int mf = 0; mf < 4; ++mf) {
        int e = m0 + mf * 16 + l15;
        e = e < E ? e : E - 1;
        int s = eli[e];
        int d = eli[E + e];
        s = s < 0 ? 0 : (s >= nnodes ? nnodes - 1 : s);
        d = d < 0 ? 0 : (d >= nnodes ? nnodes - 1 : d);
        offs[mf] = (unsigned)s * 1024u;
        offd[mf] = (unsigned)d * 1024u;
    }
    const char* zbb = (const char*)zf;

    const int swz = (l15 >> 1) & 3;
    const unsigned short* bbase = &btile[0][0][0][0] + l15 * 32 + (quad ^ swz) * 8;

    auto stage = [&](int kc, int buf) {
        const char* g = (const char*)BTc + kc * 32768 + wid * 1024 + lane * 16;
        char* l = (char*)&btile[buf][0][0][0] + wid * 1024 + lane * 16;
#pragma unroll
        for (int i = 0; i < 8; ++i)
            gl_lds16(g + i * 4096, l + i * 4096);
    };

    auto load_a = [&](int ks, short8* dst) {
        const unsigned* off = (ks < 8) ? offs : offd;
        const int cb = (ks & 7) * 128 + quad * 32;
#pragma unroll
        for (int mf = 0; mf < 4; ++mf) {
            const float* pf = (const float*)(zbb + (size_t)off[mf] + cb);
            float4 f0 = *(const float4*)pf;
            float4 f1 = *(const float4*)(pf + 4);
            short8 av;
            av[0] = (short)bf16rne(f0.x); av[1] = (short)bf16rne(f0.y);
            av[2] = (short)bf16rne(f0.z); av[3] = (short)bf16rne(f0.w);
            av[4] = (short)bf16rne(f1.x); av[5] = (short)bf16rne(f1.y);
            av[6] = (short)bf16rne(f1.z); av[7] = (short)bf16rne(f1.w);
            dst[mf] = av;
        }
    };

    floatx4 acc[4][8];
#pragma unroll
    for (int mf = 0; mf < 4; ++mf)
#pragma unroll
        for (int nf = 0; nf < 8; ++nf)
            acc[mf][nf] = (floatx4){0.f, 0.f, 0.f, 0.f};

    short8 A[3][4];
    stage(0, 0);
    load_a(0, A[0]);
    load_a(1, A[1]);
    __syncthreads();

#pragma unroll
    for (int kc = 0; kc < 4; ++kc) {
        if (kc < 3) stage(kc + 1, (kc + 1) & 1);

#pragma unroll
        for (int s4 = 0; s4 < 4; ++s4) {
            const int ks = kc * 4 + s4;
            if (ks + 2 < 16) load_a(ks + 2, A[(ks + 2) % 3]);

            const unsigned short* bs = bbase + (kc & 1) * 16384 + s4 * 4096;
            short8 bfr[8];
#pragma unroll
            for (int nf = 0; nf < 8; ++nf)
                bfr[nf] = *(const short8*)(bs + nf * 512);

            const short8* ac = A[ks % 3];
#pragma unroll
            for (int nf = 0; nf < 8; ++nf)
#pragma unroll
                for (int mf = 0; mf < 4; ++mf)
                    acc[mf][nf] = __builtin_amdgcn_mfma_f32_16x16x32_bf16(
                        ac[mf], bfr[nf], acc[mf][nf], 0, 0, 0);
        }

        if (kc < 3) __syncthreads();
    }

    const float b2s = b2[0];
    float b1v[8], w2v[8];
#pragma unroll
    for (int nf = 0; nf < 8; ++nf) {
        int c = nf * 16 + l15;
        b1v[nf] = b1[c];
        w2v[nf] = W2[c];
    }
#pragma unroll
    for (int mf = 0; mf < 4; ++mf) {
#pragma unroll
        for (int r = 0; r < 4; ++r) {
            float s = 0.f;
#pragma unroll
            for (int nf = 0; nf < 8; ++nf) {
                float v = acc[mf][nf][r] + b1v[nf];
                v = v > 0.f ? v : 0.f;
                s = fmaf(v, w2v[nf], s);
            }
            s += __shfl_xor(s, 1);
            s += __shfl_xor(s, 2);
            s += __shfl_xor(s, 4);
            s += __shfl_xor(s, 8);
            if (l15 == 0) {
                int e = m0 + mf * 16 + quad * 4 + r;
                if (e < E) out[e] = s + b2s;
            }
        }
    }
}

// ---- emergency fallback (tiny ws): one block per edge, fp32 vector ----
__global__ void naive_edge(const float* __restrict__ z, const int* __restrict__ eli,
                           int E, int nnodes,
                           const float* __restrict__ W1, const float* __restrict__ b1,
                           const float* __restrict__ W2, const float* __restrict__ b2,
                           float* __restrict__ out)
{
    __shared__ float red[2];
    int e = blockIdx.x;
    int j = threadIdx.x;
    int s = eli[e], d = eli[E + e];
    s = s < 0 ? 0 : (s >= nnodes ? nnodes - 1 : s);
    d = d < 0 ? 0 : (d >= nnodes ? nnodes - 1 : d);
    const float* zs = z + (long long)s * 256;
    const float* zd = z + (long long)d * 256;
    float h = b1[j];
    for (int i = 0; i < 256; ++i) h = fmaf(zs[i], W1[i * 128 + j], h);
    for (int i = 0; i < 256; ++i) h = fmaf(zd[i], W1[(256 + i) * 128 + j], h);
    h = h > 0.f ? h : 0.f;
    float v = h * W2[j];
    v += __shfl_xor(v, 1);  v += __shfl_xor(v, 2);  v += __shfl_xor(v, 4);
    v += __shfl_xor(v, 8);  v += __shfl_xor(v, 16); v += __shfl_xor(v, 32);
    if ((threadIdx.x & 63) == 0) red[threadIdx.x >> 6] = v;
    __syncthreads();
    if (threadIdx.x == 0) out[e] = red[0] + red[1] + b2[0];
}

extern "C" void kernel_launch(void* const* d_in, const int* in_sizes, int n_in,
                              void* d_out, int out_size, void* d_ws, size_t ws_size,
                              hipStream_t stream) {
    const float* z   = (const float*)d_in[0];
    const int*   eli = (const int*)d_in[1];      // int64 in reference -> int32 on device
    const float* W1  = (const float*)d_in[2];
    const float* b1  = (const float*)d_in[3];
    const float* W2  = (const float*)d_in[4];
    const float* b2  = (const float*)d_in[5];
    float*       out = (float*)d_out;

    const int E      = in_sizes[1] / 2;
    const int nnodes = in_sizes[0] / 256;

    const size_t HB   = (size_t)nnodes * 512;    // H partials fp16 [N][256]
    const size_t BT2B = 131072;                  // two-half swizzled W1 image
    const size_t BTB  = (size_t)512 * 128 * 2;   // old single image (fallback)

    const int grid_edge = (E + 63) / 64;

    if (ws_size >= HB + BT2B) {
        // primary: stage-once zero-barrier persistent GEMM + gather edge phase
        _Float16*       Hh   = (_Float16*)d_ws;
        unsigned short* BTc2 = (unsigned short*)((char*)d_ws + HB);
        cvt_w1h<<<256, 256, 0, stream>>>(W1, BTc2);
        gemm_hp<<<512, 256, 0, stream>>>(z, nnodes, BTc2, b1, Hh);
        edge_out<<<grid_edge, 256, 0, stream>>>(Hh, eli, E, nnodes, W2, b2, out);
    } else if (ws_size >= BTB) {
        unsigned short* BTc = (unsigned short*)d_ws;
        cvt_w1<<<256, 256, 0, stream>>>(W1, BTc);
        fused_mlp_f32<<<(E + 255) / 256, 256, 0, stream>>>(z, eli, E, nnodes, BTc, b1, W2, b2, out);
    } else {
        naive_edge<<<E, 128, 0, stream>>>(z, eli, E, nnodes, W1, b1, W2, b2, out);
    }
}

// Round 9
// 248.085 us; speedup vs baseline: 1.2745x; 1.2745x over previous
//
#include <hip/hip_runtime.h>
#include <hip/hip_bf16.h>

// LinkPredictorGAT: out[e] = relu(concat(z[src[e]], z[dst[e]]) @ W1 + b1) @ W2 + b2
// R17 = REVERT gemm to the measured-best R11 structure + one edge_out probe.
// gemm structure ladder (measured): R11 62us < R12 68 < R15 78 < R14 100 < R16 135.
//   R11: z read ONCE, BK=64 dbuf LDS (64KB), 3 mid barriers, 128-row tiles,
//   wave = 32 rows x 256 cols (both H halves share the A row). Restored verbatim.
// edge_out probe: 8 edges/thread (16 gathers in flight, was 8). Discriminates
//   latency-bound (dur -> ~60us) vs L3-fabric-rate-bound (dur unchanged -> floor).
//   R12 already proved not VALU-bound (VALUBusy 43->27% at identical 68.5us).

typedef __attribute__((ext_vector_type(4))) float floatx4;
typedef __attribute__((ext_vector_type(8))) short short8;
typedef _Float16 half8v __attribute__((ext_vector_type(8)));
typedef __fp16 fp16x2 __attribute__((ext_vector_type(2)));

#if defined(__has_builtin)
#if __has_builtin(__builtin_amdgcn_fdot2)
#define HAVE_FDOT2 1
#endif
#endif

__device__ __forceinline__ unsigned short bf16rne(float x) {
    unsigned int u = __float_as_uint(x);
    u += 0x7fffu + ((u >> 16) & 1u);
    return (unsigned short)(u >> 16);
}

// async global->LDS, 16 B per lane; LDS dest = wave-uniform base + lane*16.
__device__ __forceinline__ void gl_lds16(const void* g, void* l) {
    __builtin_amdgcn_global_load_lds(
        (const __attribute__((address_space(1))) void*)(unsigned long long)g,
        (__attribute__((address_space(3))) void*)(unsigned)(unsigned long long)l,
        16, 0, 0);
}

// ---- W1 [512][128] fp32 -> BTc2: two per-half swizzled linear images ----
// Per half (k_local in [0,256)): L(s,n,g',j) = s*4096 + n*32 + g'*8 + j shorts;
// s = k_local>>5, g = (k_local>>3)&3, j = k_local&7, g' = g ^ ((n>>1)&3).
// Half h occupies shorts [h*32768, +32768). Reader: 0 bank conflicts (verified).
__global__ void cvt_w1h(const float* __restrict__ W1, unsigned short* __restrict__ BTc2) {
    int t = blockIdx.x * blockDim.x + threadIdx.x;   // 0..65535
    int hf = t >> 15, rem = t & 32767;
    int s = rem >> 12, rem2 = rem & 4095;
    int n = rem2 >> 5, rem3 = rem2 & 31;
    int gp = rem3 >> 3, j = rem3 & 7;
    int g = gp ^ ((n >> 1) & 3);
    int k = hf * 256 + s * 32 + g * 8 + j;
    BTc2[t] = bf16rne(W1[k * 128 + n]);
}

// ---- old-path W1 image (512 rows), kept for the low-workspace fallback ----
__global__ void cvt_w1(const float* __restrict__ W1, unsigned short* __restrict__ BTc) {
    int t = blockIdx.x * blockDim.x + threadIdx.x;   // 0..65535
    int s = t >> 12, rem = t & 4095;
    int n = rem >> 5, rem2 = rem & 31;
    int gp = rem2 >> 3, j = rem2 & 7;
    int g = gp ^ ((n >> 1) & 3);
    int k = s * 32 + g * 8 + j;
    BTc[t] = bf16rne(W1[k * 128 + n]);
}

// ---- precompute GEMM, both halves per block (R11 verbatim; measured 62us) ----
// H[row][0:128] = z[row]@W1a + b1 ; H[row][128:256] = z[row]@W1b  (fp16 out)
// 256 thr / 4 waves; wave = 32 rows x 256 cols (mf=2, nf=16); block = 128 rows.
// K=256 as 4 chunks of BK=64; per chunk both halves' B staged (2 x 16 KB);
// double-buffered = 64 KB -> 2 blocks/CU. A read fp32, converted in-register.
__global__ __launch_bounds__(256, 2)
void gemm_hb(const float* __restrict__ zf, int nnodes,
             const unsigned short* __restrict__ BTc2,
             const float* __restrict__ b1, _Float16* __restrict__ Hh)
{
    // [buf][half][slab(K32)][n(128)][32] shorts = 64 KB
    __shared__ unsigned short btile[2][2][2][128][32];

    const int t = threadIdx.x;
    const int wid = t >> 6;
    const int lane = t & 63;
    const int l15 = lane & 15;
    const int quad = lane >> 4;
    const int m0 = blockIdx.x * 128 + wid * 32;

    unsigned offs[2];
#pragma unroll
    for (int mf = 0; mf < 2; ++mf) {
        int r = m0 + mf * 16 + l15;
        r = r < nnodes ? r : nnodes - 1;              // clamp tail (stores masked)
        offs[mf] = (unsigned)r * 1024u;               // fp32 row = 1024 B
    }
    const char* zbb = (const char*)zf;

    const int swz = (l15 >> 1) & 3;
    const unsigned short* bbase = &btile[0][0][0][0][0] + l15 * 32 + (quad ^ swz) * 8;

    // stage chunk kc (BK=64: 2 slabs per half, 16 KB per half) into buf
    auto stage = [&](int kc, int buf) {
        char* lbase = (char*)&btile[0][0][0][0][0] + buf * 32768 + wid * 1024 + lane * 16;
        const char* gbase = (const char*)BTc2 + kc * 16384 + wid * 1024 + lane * 16;
#pragma unroll
        for (int h = 0; h < 2; ++h) {
            const char* g = gbase + h * 65536;
            char* l = lbase + h * 16384;
#pragma unroll
            for (int i = 0; i < 4; ++i)
                gl_lds16(g + i * 4096, l + i * 4096);
        }
    };

    // A loader: K-step ks in [0,8) (K32 each); fp32 -> bf16 in-register (RNE)
    auto load_a = [&](int ks, short8* dst) {
        const int cb = ks * 128 + quad * 32;
#pragma unroll
        for (int mf = 0; mf < 2; ++mf) {
            const float* pf = (const float*)(zbb + (size_t)offs[mf] + cb);
            float4 f0 = *(const float4*)pf;
            float4 f1 = *(const float4*)(pf + 4);
            short8 av;
            av[0] = (short)bf16rne(f0.x); av[1] = (short)bf16rne(f0.y);
            av[2] = (short)bf16rne(f0.z); av[3] = (short)bf16rne(f0.w);
            av[4] = (short)bf16rne(f1.x); av[5] = (short)bf16rne(f1.y);
            av[6] = (short)bf16rne(f1.z); av[7] = (short)bf16rne(f1.w);
            dst[mf] = av;
        }
    };

    floatx4 acc[2][16];
#pragma unroll
    for (int mf = 0; mf < 2; ++mf)
#pragma unroll
        for (int nf = 0; nf < 16; ++nf)
            acc[mf][nf] = (floatx4){0.f, 0.f, 0.f, 0.f};

    short8 A[3][2];                                   // depth-3 rolling A prefetch
    stage(0, 0);
    load_a(0, A[0]);
    load_a(1, A[1]);
    __syncthreads();

#pragma unroll
    for (int kc = 0; kc < 4; ++kc) {                  // 4 chunks of BK=64
        if (kc < 3) stage(kc + 1, (kc + 1) & 1);

#pragma unroll
        for (int s4 = 0; s4 < 2; ++s4) {              // 2 K32 slabs per chunk
            const int ks = kc * 2 + s4;
            if (ks + 2 < 8) load_a(ks + 2, A[(ks + 2) % 3]);

            const unsigned short* bs0 = bbase + (kc & 1) * 16384 + s4 * 4096;  // half0
            const short8* ac = A[ks % 3];

#pragma unroll
            for (int gq = 0; gq < 4; ++gq) {          // 4 groups of 4 nf (2 per half)
                const unsigned short* bs = bs0 + (gq >> 1) * 8192 + (gq & 1) * 2048;
                short8 bfr[4];
#pragma unroll
                for (int nf = 0; nf < 4; ++nf)
                    bfr[nf] = *(const short8*)(bs + nf * 512);  // swizzled: 0 conflicts
#pragma unroll
                for (int nf = 0; nf < 4; ++nf)
#pragma unroll
                    for (int mf = 0; mf < 2; ++mf)
                        acc[mf][gq * 4 + nf] = __builtin_amdgcn_mfma_f32_16x16x32_bf16(
                            ac[mf], bfr[nf], acc[mf][gq * 4 + nf], 0, 0, 0);
            }
        }

        if (kc < 3) __syncthreads();
    }

    // epilogue: C/D col = l15 + 16*(nf&7), half = nf>>3; row = quad*4 + r (+16mf)
    float b1v[8];
#pragma unroll
    for (int nf = 0; nf < 8; ++nf)
        b1v[nf] = b1[nf * 16 + l15];
#pragma unroll
    for (int mf = 0; mf < 2; ++mf) {
#pragma unroll
        for (int r = 0; r < 4; ++r) {
            int row = m0 + mf * 16 + quad * 4 + r;
            if (row < nnodes) {
                _Float16* hp = Hh + (size_t)row * 256 + l15;
#pragma unroll
                for (int nf = 0; nf < 8; ++nf)
                    hp[nf * 16] = (_Float16)(acc[mf][nf][r] + b1v[nf]);
#pragma unroll
                for (int nf = 0; nf < 8; ++nf)
                    hp[128 + nf * 16] = (_Float16)acc[mf][8 + nf][r];
            }
        }
    }
}

// ---- edge phase: pure gather + packed-fp16 relu-dot; 8 edges/thread probe ----
// 16 lanes/edge; block = 256 thr covers 128 edges; 16 gathers in flight/thread.
__global__ __launch_bounds__(256)
void edge_out(const _Float16* __restrict__ Hh, const int* __restrict__ eli,
              int E, int nnodes,
              const float* __restrict__ W2, const float* __restrict__ b2,
              float* __restrict__ out)
{
    const int t = threadIdx.x;
    const int lane = t & 63;
    const int wid = t >> 6;
    const int l15 = lane & 15;
    const int grp = lane >> 4;

    fp16x2 w2h[4];
#pragma unroll
    for (int p = 0; p < 4; ++p) {
        w2h[p][0] = (__fp16)W2[l15 * 8 + 2 * p];
        w2h[p][1] = (__fp16)W2[l15 * 8 + 2 * p + 1];
    }
    const float b2s = b2[0];

    const int e0 = blockIdx.x * 128 + wid * 32 + grp;

    half8v hs[8], hd[8];
    int ee[8];
#pragma unroll
    for (int i = 0; i < 8; ++i) {
        int e = e0 + i * 4;
        ee[i] = e;
        int ec = e < E ? e : E - 1;
        int s = eli[ec];
        int d = eli[E + ec];
        s = s < 0 ? 0 : (s >= nnodes ? nnodes - 1 : s);
        d = d < 0 ? 0 : (d >= nnodes ? nnodes - 1 : d);
        hs[i] = *(const half8v*)(Hh + (size_t)s * 256 + l15 * 8);
        hd[i] = *(const half8v*)(Hh + (size_t)d * 256 + 128 + l15 * 8);
    }
    const half8v zero = {};
#pragma unroll
    for (int i = 0; i < 8; ++i) {
        half8v v = hs[i] + hd[i];                         // v_pk_add_f16 x4
        v = __builtin_elementwise_max(v, zero);           // v_pk_max_f16 x4
        float sacc = 0.f;
#if defined(HAVE_FDOT2)
#pragma unroll
        for (int p = 0; p < 4; ++p) {
            fp16x2 a;
            a[0] = (__fp16)v[2 * p];
            a[1] = (__fp16)v[2 * p + 1];
            sacc = __builtin_amdgcn_fdot2(a, w2h[p], sacc, false);  // v_dot2_f32_f16
        }
#else
#pragma unroll
        for (int p = 0; p < 4; ++p) {
            sacc = fmaf((float)v[2 * p],     (float)w2h[p][0], sacc);
            sacc = fmaf((float)v[2 * p + 1], (float)w2h[p][1], sacc);
        }
#endif
        sacc += __shfl_xor(sacc, 1);
        sacc += __shfl_xor(sacc, 2);
        sacc += __shfl_xor(sacc, 4);
        sacc += __shfl_xor(sacc, 8);
        if (l15 == 0 && ee[i] < E)
            out[ee[i]] = sacc + b2s;
    }
}

// ---- R8 fused kernel (fp32-A variant), kept for the low-workspace fallback ----
__global__ __launch_bounds__(256, 2)
void fused_mlp_f32(const float* __restrict__ zf, const int* __restrict__ eli,
                   int E, int nnodes,
                   const unsigned short* __restrict__ BTc,
                   const float* __restrict__ b1, const float* __restrict__ W2,
                   const float* __restrict__ b2, float* __restrict__ out)
{
    __shared__ unsigned short btile[2][4][128][32];

    const int t = threadIdx.x;
    const int wid = t >> 6;
    const int lane = t & 63;
    const int l15 = lane & 15;
    const int quad = lane >> 4;
    const int m0 = blockIdx.x * 256 + wid * 64;

    unsigned offs[4], offd[4];
#pragma unroll
    for (int mf = 0; mf < 4; ++mf) {
        int e = m0 + mf * 16 + l15;
        e = e < E ? e : E - 1;
        int s = eli[e];
        int d = eli[E + e];
        s = s < 0 ? 0 : (s >= nnodes ? nnodes - 1 : s);
        d = d < 0 ? 0 : (d >= nnodes ? nnodes - 1 : d);
        offs[mf] = (unsigned)s * 1024u;
        offd[mf] = (unsigned)d * 1024u;
    }
    const char* zbb = (const char*)zf;

    const int swz = (l15 >> 1) & 3;
    const unsigned short* bbase = &btile[0][0][0][0] + l15 * 32 + (quad ^ swz) * 8;

    auto stage = [&](int kc, int buf) {
        const char* g = (const char*)BTc + kc * 32768 + wid * 1024 + lane * 16;
        char* l = (char*)&btile[buf][0][0][0] + wid * 1024 + lane * 16;
#pragma unroll
        for (int i = 0; i < 8; ++i)
            gl_lds16(g + i * 4096, l + i * 4096);
    };

    auto load_a = [&](int ks, short8* dst) {
        const unsigned* off = (ks < 8) ? offs : offd;
        const int cb = (ks & 7) * 128 + quad * 32;
#pragma unroll
        for (int mf = 0; mf < 4; ++mf) {
            const float* pf = (const float*)(zbb + (size_t)off[mf] + cb);
            float4 f0 = *(const float4*)pf;
            float4 f1 = *(const float4*)(pf + 4);
            short8 av;
            av[0] = (short)bf16rne(f0.x); av[1] = (short)bf16rne(f0.y);
            av[2] = (short)bf16rne(f0.z); av[3] = (short)bf16rne(f0.w);
            av[4] = (short)bf16rne(f1.x); av[5] = (short)bf16rne(f1.y);
            av[6] = (short)bf16rne(f1.z); av[7] = (short)bf16rne(f1.w);
            dst[mf] = av;
        }
    };

    floatx4 acc[4][8];
#pragma unroll
    for (int mf = 0; mf < 4; ++mf)
#pragma unroll
        for (int nf = 0; nf < 8; ++nf)
            acc[mf][nf] = (floatx4){0.f, 0.f, 0.f, 0.f};

    short8 A[3][4];
    stage(0, 0);
    load_a(0, A[0]);
    load_a(1, A[1]);
    __syncthreads();

#pragma unroll
    for (int kc = 0; kc < 4; ++kc) {
        if (kc < 3) stage(kc + 1, (kc + 1) & 1);

#pragma unroll
        for (int s4 = 0; s4 < 4; ++s4) {
            const int ks = kc * 4 + s4;
            if (ks + 2 < 16) load_a(ks + 2, A[(ks + 2) % 3]);

            const unsigned short* bs = bbase + (kc & 1) * 16384 + s4 * 4096;
            short8 bfr[8];
#pragma unroll
            for (int nf = 0; nf < 8; ++nf)
                bfr[nf] = *(const short8*)(bs + nf * 512);

            const short8* ac = A[ks % 3];
#pragma unroll
            for (int nf = 0; nf < 8; ++nf)
#pragma unroll
                for (int mf = 0; mf < 4; ++mf)
                    acc[mf][nf] = __builtin_amdgcn_mfma_f32_16x16x32_bf16(
                        ac[mf], bfr[nf], acc[mf][nf], 0, 0, 0);
        }

        if (kc < 3) __syncthreads();
    }

    const float b2s = b2[0];
    float b1v[8], w2v[8];
#pragma unroll
    for (int nf = 0; nf < 8; ++nf) {
        int c = nf * 16 + l15;
        b1v[nf] = b1[c];
        w2v[nf] = W2[c];
    }
#pragma unroll
    for (int mf = 0; mf < 4; ++mf) {
#pragma unroll
        for (int r = 0; r < 4; ++r) {
            float s = 0.f;
#pragma unroll
            for (int nf = 0; nf < 8; ++nf) {
                float v = acc[mf][nf][r] + b1v[nf];
                v = v > 0.f ? v : 0.f;
                s = fmaf(v, w2v[nf], s);
            }
            s += __shfl_xor(s, 1);
            s += __shfl_xor(s, 2);
            s += __shfl_xor(s, 4);
            s += __shfl_xor(s, 8);
            if (l15 == 0) {
                int e = m0 + mf * 16 + quad * 4 + r;
                if (e < E) out[e] = s + b2s;
            }
        }
    }
}

// ---- emergency fallback (tiny ws): one block per edge, fp32 vector ----
__global__ void naive_edge(const float* __restrict__ z, const int* __restrict__ eli,
                           int E, int nnodes,
                           const float* __restrict__ W1, const float* __restrict__ b1,
                           const float* __restrict__ W2, const float* __restrict__ b2,
                           float* __restrict__ out)
{
    __shared__ float red[2];
    int e = blockIdx.x;
    int j = threadIdx.x;
    int s = eli[e], d = eli[E + e];
    s = s < 0 ? 0 : (s >= nnodes ? nnodes - 1 : s);
    d = d < 0 ? 0 : (d >= nnodes ? nnodes - 1 : d);
    const float* zs = z + (long long)s * 256;
    const float* zd = z + (long long)d * 256;
    float h = b1[j];
    for (int i = 0; i < 256; ++i) h = fmaf(zs[i], W1[i * 128 + j], h);
    for (int i = 0; i < 256; ++i) h = fmaf(zd[i], W1[(256 + i) * 128 + j], h);
    h = h > 0.f ? h : 0.f;
    float v = h * W2[j];
    v += __shfl_xor(v, 1);  v += __shfl_xor(v, 2);  v += __shfl_xor(v, 4);
    v += __shfl_xor(v, 8);  v += __shfl_xor(v, 16); v += __shfl_xor(v, 32);
    if ((threadIdx.x & 63) == 0) red[threadIdx.x >> 6] = v;
    __syncthreads();
    if (threadIdx.x == 0) out[e] = red[0] + red[1] + b2[0];
}

extern "C" void kernel_launch(void* const* d_in, const int* in_sizes, int n_in,
                              void* d_out, int out_size, void* d_ws, size_t ws_size,
                              hipStream_t stream) {
    const float* z   = (const float*)d_in[0];
    const int*   eli = (const int*)d_in[1];      // int64 in reference -> int32 on device
    const float* W1  = (const float*)d_in[2];
    const float* b1  = (const float*)d_in[3];
    const float* W2  = (const float*)d_in[4];
    const float* b2  = (const float*)d_in[5];
    float*       out = (float*)d_out;

    const int E      = in_sizes[1] / 2;
    const int nnodes = in_sizes[0] / 256;

    const size_t HB   = (size_t)nnodes * 512;    // H partials fp16 [N][256]
    const size_t BT2B = 131072;                  // two-half swizzled W1 image
    const size_t BTB  = (size_t)512 * 128 * 2;   // old single image (fallback)

    const int grid_gemm = (nnodes + 127) / 128;
    const int grid_edge = (E + 127) / 128;

    if (ws_size >= HB + BT2B) {
        // primary: R11 precompute GEMM + 8-edges/thread gather edge phase
        _Float16*       Hh   = (_Float16*)d_ws;
        unsigned short* BTc2 = (unsigned short*)((char*)d_ws + HB);
        cvt_w1h<<<256, 256, 0, stream>>>(W1, BTc2);
        gemm_hb<<<grid_gemm, 256, 0, stream>>>(z, nnodes, BTc2, b1, Hh);
        edge_out<<<grid_edge, 256, 0, stream>>>(Hh, eli, E, nnodes, W2, b2, out);
    } else if (ws_size >= BTB) {
        unsigned short* BTc = (unsigned short*)d_ws;
        cvt_w1<<<256, 256, 0, stream>>>(W1, BTc);
        fused_mlp_f32<<<(E + 255) / 256, 256, 0, stream>>>(z, eli, E, nnodes, BTc, b1, W2, b2, out);
    } else {
        naive_edge<<<E, 128, 0, stream>>>(z, eli, E, nnodes, W1, b1, W2, b2, out);
    }
}

// Round 10
// 247.631 us; speedup vs baseline: 1.2768x; 1.0018x over previous
//
#include <hip/hip_runtime.h>
#include <hip/hip_bf16.h>

// LinkPredictorGAT: out[e] = relu(concat(z[src[e]], z[dst[e]]) @ W1 + b1) @ W2 + b2
// R18 = R11 gemm + depth-4 A prefetch; edge_out reverted to 4-edges/thread.
// Ledger: edge_out PROVEN rate-bound (~3.5 TB/s L3 random-gather): R12 VALU-halving
//   null + R17 2x-loads-in-flight null. 68.5us = structural floor for this algorithm.
// gemm ladder: R11 62us < R12 68 < R15 78 (8 barriers/occupancy) < R14 100 (no LDS)
//   < R16 135 (persistent). All counters say the residual stall is A-load latency
//   (HBM ~700-900cy vs depth-3 cover ~400cy; nothing else saturated). Depth-4 adds
//   +16 VGPR -> ~254/256 unified at 2 waves/SIMD; A is streaming so no R9-style
//   locality loss.

typedef __attribute__((ext_vector_type(4))) float floatx4;
typedef __attribute__((ext_vector_type(8))) short short8;
typedef _Float16 half8v __attribute__((ext_vector_type(8)));
typedef __fp16 fp16x2 __attribute__((ext_vector_type(2)));

#if defined(__has_builtin)
#if __has_builtin(__builtin_amdgcn_fdot2)
#define HAVE_FDOT2 1
#endif
#endif

__device__ __forceinline__ unsigned short bf16rne(float x) {
    unsigned int u = __float_as_uint(x);
    u += 0x7fffu + ((u >> 16) & 1u);
    return (unsigned short)(u >> 16);
}

// async global->LDS, 16 B per lane; LDS dest = wave-uniform base + lane*16.
__device__ __forceinline__ void gl_lds16(const void* g, void* l) {
    __builtin_amdgcn_global_load_lds(
        (const __attribute__((address_space(1))) void*)(unsigned long long)g,
        (__attribute__((address_space(3))) void*)(unsigned)(unsigned long long)l,
        16, 0, 0);
}

// ---- W1 [512][128] fp32 -> BTc2: two per-half swizzled linear images ----
// Per half (k_local in [0,256)): L(s,n,g',j) = s*4096 + n*32 + g'*8 + j shorts;
// s = k_local>>5, g = (k_local>>3)&3, j = k_local&7, g' = g ^ ((n>>1)&3).
// Half h occupies shorts [h*32768, +32768). Reader: 0 bank conflicts (verified).
__global__ void cvt_w1h(const float* __restrict__ W1, unsigned short* __restrict__ BTc2) {
    int t = blockIdx.x * blockDim.x + threadIdx.x;   // 0..65535
    int hf = t >> 15, rem = t & 32767;
    int s = rem >> 12, rem2 = rem & 4095;
    int n = rem2 >> 5, rem3 = rem2 & 31;
    int gp = rem3 >> 3, j = rem3 & 7;
    int g = gp ^ ((n >> 1) & 3);
    int k = hf * 256 + s * 32 + g * 8 + j;
    BTc2[t] = bf16rne(W1[k * 128 + n]);
}

// ---- old-path W1 image (512 rows), kept for the low-workspace fallback ----
__global__ void cvt_w1(const float* __restrict__ W1, unsigned short* __restrict__ BTc) {
    int t = blockIdx.x * blockDim.x + threadIdx.x;   // 0..65535
    int s = t >> 12, rem = t & 4095;
    int n = rem >> 5, rem2 = rem & 31;
    int gp = rem2 >> 3, j = rem2 & 7;
    int g = gp ^ ((n >> 1) & 3);
    int k = s * 32 + g * 8 + j;
    BTc[t] = bf16rne(W1[k * 128 + n]);
}

// ---- precompute GEMM, both halves per block (R11 + depth-4 A prefetch) ----
// H[row][0:128] = z[row]@W1a + b1 ; H[row][128:256] = z[row]@W1b  (fp16 out)
// 256 thr / 4 waves; wave = 32 rows x 256 cols (mf=2, nf=16); block = 128 rows.
// K=256 as 4 chunks of BK=64; per chunk both halves' B staged (2 x 16 KB);
// double-buffered = 64 KB -> 2 blocks/CU. A read fp32, converted in-register.
__global__ __launch_bounds__(256, 2)
void gemm_hb(const float* __restrict__ zf, int nnodes,
             const unsigned short* __restrict__ BTc2,
             const float* __restrict__ b1, _Float16* __restrict__ Hh)
{
    // [buf][half][slab(K32)][n(128)][32] shorts = 64 KB
    __shared__ unsigned short btile[2][2][2][128][32];

    const int t = threadIdx.x;
    const int wid = t >> 6;
    const int lane = t & 63;
    const int l15 = lane & 15;
    const int quad = lane >> 4;
    const int m0 = blockIdx.x * 128 + wid * 32;

    unsigned offs[2];
#pragma unroll
    for (int mf = 0; mf < 2; ++mf) {
        int r = m0 + mf * 16 + l15;
        r = r < nnodes ? r : nnodes - 1;              // clamp tail (stores masked)
        offs[mf] = (unsigned)r * 1024u;               // fp32 row = 1024 B
    }
    const char* zbb = (const char*)zf;

    const int swz = (l15 >> 1) & 3;
    const unsigned short* bbase = &btile[0][0][0][0][0] + l15 * 32 + (quad ^ swz) * 8;

    // stage chunk kc (BK=64: 2 slabs per half, 16 KB per half) into buf
    auto stage = [&](int kc, int buf) {
        char* lbase = (char*)&btile[0][0][0][0][0] + buf * 32768 + wid * 1024 + lane * 16;
        const char* gbase = (const char*)BTc2 + kc * 16384 + wid * 1024 + lane * 16;
#pragma unroll
        for (int h = 0; h < 2; ++h) {
            const char* g = gbase + h * 65536;
            char* l = lbase + h * 16384;
#pragma unroll
            for (int i = 0; i < 4; ++i)
                gl_lds16(g + i * 4096, l + i * 4096);
        }
    };

    // A loader: K-step ks in [0,8) (K32 each); fp32 -> bf16 in-register (RNE)
    auto load_a = [&](int ks, short8* dst) {
        const int cb = ks * 128 + quad * 32;
#pragma unroll
        for (int mf = 0; mf < 2; ++mf) {
            const float* pf = (const float*)(zbb + (size_t)offs[mf] + cb);
            float4 f0 = *(const float4*)pf;
            float4 f1 = *(const float4*)(pf + 4);
            short8 av;
            av[0] = (short)bf16rne(f0.x); av[1] = (short)bf16rne(f0.y);
            av[2] = (short)bf16rne(f0.z); av[3] = (short)bf16rne(f0.w);
            av[4] = (short)bf16rne(f1.x); av[5] = (short)bf16rne(f1.y);
            av[6] = (short)bf16rne(f1.z); av[7] = (short)bf16rne(f1.w);
            dst[mf] = av;
        }
    };

    floatx4 acc[2][16];
#pragma unroll
    for (int mf = 0; mf < 2; ++mf)
#pragma unroll
        for (int nf = 0; nf < 16; ++nf)
            acc[mf][nf] = (floatx4){0.f, 0.f, 0.f, 0.f};

    short8 A[4][2];                                   // depth-4 rolling A prefetch
    stage(0, 0);
    load_a(0, A[0]);
    load_a(1, A[1]);
    load_a(2, A[2]);
    __syncthreads();

#pragma unroll
    for (int kc = 0; kc < 4; ++kc) {                  // 4 chunks of BK=64
        if (kc < 3) stage(kc + 1, (kc + 1) & 1);

#pragma unroll
        for (int s4 = 0; s4 < 2; ++s4) {              // 2 K32 slabs per chunk
            const int ks = kc * 2 + s4;
            if (ks + 3 < 8) load_a(ks + 3, A[(ks + 3) & 3]);

            const unsigned short* bs0 = bbase + (kc & 1) * 16384 + s4 * 4096;  // half0
            const short8* ac = A[ks & 3];

#pragma unroll
            for (int gq = 0; gq < 4; ++gq) {          // 4 groups of 4 nf (2 per half)
                const unsigned short* bs = bs0 + (gq >> 1) * 8192 + (gq & 1) * 2048;
                short8 bfr[4];
#pragma unroll
                for (int nf = 0; nf < 4; ++nf)
                    bfr[nf] = *(const short8*)(bs + nf * 512);  // swizzled: 0 conflicts
#pragma unroll
                for (int nf = 0; nf < 4; ++nf)
#pragma unroll
                    for (int mf = 0; mf < 2; ++mf)
                        acc[mf][gq * 4 + nf] = __builtin_amdgcn_mfma_f32_16x16x32_bf16(
                            ac[mf], bfr[nf], acc[mf][gq * 4 + nf], 0, 0, 0);
            }
        }

        if (kc < 3) __syncthreads();
    }

    // epilogue: C/D col = l15 + 16*(nf&7), half = nf>>3; row = quad*4 + r (+16mf)
    float b1v[8];
#pragma unroll
    for (int nf = 0; nf < 8; ++nf)
        b1v[nf] = b1[nf * 16 + l15];
#pragma unroll
    for (int mf = 0; mf < 2; ++mf) {
#pragma unroll
        for (int r = 0; r < 4; ++r) {
            int row = m0 + mf * 16 + quad * 4 + r;
            if (row < nnodes) {
                _Float16* hp = Hh + (size_t)row * 256 + l15;
#pragma unroll
                for (int nf = 0; nf < 8; ++nf)
                    hp[nf * 16] = (_Float16)(acc[mf][nf][r] + b1v[nf]);
#pragma unroll
                for (int nf = 0; nf < 8; ++nf)
                    hp[128 + nf * 16] = (_Float16)acc[mf][8 + nf][r];
            }
        }
    }
}

// ---- edge phase: pure gather + packed-fp16 relu-dot (4 edges/thread; proven floor) ----
// 16 lanes/edge, 4 edges per thread-slot; block = 256 thr covers 64 edges.
__global__ __launch_bounds__(256)
void edge_out(const _Float16* __restrict__ Hh, const int* __restrict__ eli,
              int E, int nnodes,
              const float* __restrict__ W2, const float* __restrict__ b2,
              float* __restrict__ out)
{
    const int t = threadIdx.x;
    const int lane = t & 63;
    const int wid = t >> 6;
    const int l15 = lane & 15;
    const int grp = lane >> 4;

    fp16x2 w2h[4];
#pragma unroll
    for (int p = 0; p < 4; ++p) {
        w2h[p][0] = (__fp16)W2[l15 * 8 + 2 * p];
        w2h[p][1] = (__fp16)W2[l15 * 8 + 2 * p + 1];
    }
    const float b2s = b2[0];

    const int e0 = blockIdx.x * 64 + wid * 16 + grp;

    half8v hs[4], hd[4];
    int ee[4];
#pragma unroll
    for (int i = 0; i < 4; ++i) {
        int e = e0 + i * 4;
        ee[i] = e;
        int ec = e < E ? e : E - 1;
        int s = eli[ec];
        int d = eli[E + ec];
        s = s < 0 ? 0 : (s >= nnodes ? nnodes - 1 : s);
        d = d < 0 ? 0 : (d >= nnodes ? nnodes - 1 : d);
        hs[i] = *(const half8v*)(Hh + (size_t)s * 256 + l15 * 8);
        hd[i] = *(const half8v*)(Hh + (size_t)d * 256 + 128 + l15 * 8);
    }
    const half8v zero = {};
#pragma unroll
    for (int i = 0; i < 4; ++i) {
        half8v v = hs[i] + hd[i];                         // v_pk_add_f16 x4
        v = __builtin_elementwise_max(v, zero);           // v_pk_max_f16 x4
        float sacc = 0.f;
#if defined(HAVE_FDOT2)
#pragma unroll
        for (int p = 0; p < 4; ++p) {
            fp16x2 a;
            a[0] = (__fp16)v[2 * p];
            a[1] = (__fp16)v[2 * p + 1];
            sacc = __builtin_amdgcn_fdot2(a, w2h[p], sacc, false);  // v_dot2_f32_f16
        }
#else
#pragma unroll
        for (int p = 0; p < 4; ++p) {
            sacc = fmaf((float)v[2 * p],     (float)w2h[p][0], sacc);
            sacc = fmaf((float)v[2 * p + 1], (float)w2h[p][1], sacc);
        }
#endif
        sacc += __shfl_xor(sacc, 1);
        sacc += __shfl_xor(sacc, 2);
        sacc += __shfl_xor(sacc, 4);
        sacc += __shfl_xor(sacc, 8);
        if (l15 == 0 && ee[i] < E)
            out[ee[i]] = sacc + b2s;
    }
}

// ---- R8 fused kernel (fp32-A variant), kept for the low-workspace fallback ----
__global__ __launch_bounds__(256, 2)
void fused_mlp_f32(const float* __restrict__ zf, const int* __restrict__ eli,
                   int E, int nnodes,
                   const unsigned short* __restrict__ BTc,
                   const float* __restrict__ b1, const float* __restrict__ W2,
                   const float* __restrict__ b2, float* __restrict__ out)
{
    __shared__ unsigned short btile[2][4][128][32];

    const int t = threadIdx.x;
    const int wid = t >> 6;
    const int lane = t & 63;
    const int l15 = lane & 15;
    const int quad = lane >> 4;
    const int m0 = blockIdx.x * 256 + wid * 64;

    unsigned offs[4], offd[4];
#pragma unroll
    for (int mf = 0; mf < 4; ++mf) {
        int e = m0 + mf * 16 + l15;
        e = e < E ? e : E - 1;
        int s = eli[e];
        int d = eli[E + e];
        s = s < 0 ? 0 : (s >= nnodes ? nnodes - 1 : s);
        d = d < 0 ? 0 : (d >= nnodes ? nnodes - 1 : d);
        offs[mf] = (unsigned)s * 1024u;
        offd[mf] = (unsigned)d * 1024u;
    }
    const char* zbb = (const char*)zf;

    const int swz = (l15 >> 1) & 3;
    const unsigned short* bbase = &btile[0][0][0][0] + l15 * 32 + (quad ^ swz) * 8;

    auto stage = [&](int kc, int buf) {
        const char* g = (const char*)BTc + kc * 32768 + wid * 1024 + lane * 16;
        char* l = (char*)&btile[buf][0][0][0] + wid * 1024 + lane * 16;
#pragma unroll
        for (int i = 0; i < 8; ++i)
            gl_lds16(g + i * 4096, l + i * 4096);
    };

    auto load_a = [&](int ks, short8* dst) {
        const unsigned* off = (ks < 8) ? offs : offd;
        const int cb = (ks & 7) * 128 + quad * 32;
#pragma unroll
        for (int mf = 0; mf < 4; ++mf) {
            const float* pf = (const float*)(zbb + (size_t)off[mf] + cb);
            float4 f0 = *(const float4*)pf;
            float4 f1 = *(const float4*)(pf + 4);
            short8 av;
            av[0] = (short)bf16rne(f0.x); av[1] = (short)bf16rne(f0.y);
            av[2] = (short)bf16rne(f0.z); av[3] = (short)bf16rne(f0.w);
            av[4] = (short)bf16rne(f1.x); av[5] = (short)bf16rne(f1.y);
            av[6] = (short)bf16rne(f1.z); av[7] = (short)bf16rne(f1.w);
            dst[mf] = av;
        }
    };

    floatx4 acc[4][8];
#pragma unroll
    for (int mf = 0; mf < 4; ++mf)
#pragma unroll
        for (int nf = 0; nf < 8; ++nf)
            acc[mf][nf] = (floatx4){0.f, 0.f, 0.f, 0.f};

    short8 A[3][4];
    stage(0, 0);
    load_a(0, A[0]);
    load_a(1, A[1]);
    __syncthreads();

#pragma unroll
    for (int kc = 0; kc < 4; ++kc) {
        if (kc < 3) stage(kc + 1, (kc + 1) & 1);

#pragma unroll
        for (int s4 = 0; s4 < 4; ++s4) {
            const int ks = kc * 4 + s4;
            if (ks + 2 < 16) load_a(ks + 2, A[(ks + 2) % 3]);

            const unsigned short* bs = bbase + (kc & 1) * 16384 + s4 * 4096;
            short8 bfr[8];
#pragma unroll
            for (int nf = 0; nf < 8; ++nf)
                bfr[nf] = *(const short8*)(bs + nf * 512);

            const short8* ac = A[ks % 3];
#pragma unroll
            for (int nf = 0; nf < 8; ++nf)
#pragma unroll
                for (int mf = 0; mf < 4; ++mf)
                    acc[mf][nf] = __builtin_amdgcn_mfma_f32_16x16x32_bf16(
                        ac[mf], bfr[nf], acc[mf][nf], 0, 0, 0);
        }

        if (kc < 3) __syncthreads();
    }

    const float b2s = b2[0];
    float b1v[8], w2v[8];
#pragma unroll
    for (int nf = 0; nf < 8; ++nf) {
        int c = nf * 16 + l15;
        b1v[nf] = b1[c];
        w2v[nf] = W2[c];
    }
#pragma unroll
    for (int mf = 0; mf < 4; ++mf) {
#pragma unroll
        for (int r = 0; r < 4; ++r) {
            float s = 0.f;
#pragma unroll
            for (int nf = 0; nf < 8; ++nf) {
                float v = acc[mf][nf][r] + b1v[nf];
                v = v > 0.f ? v : 0.f;
                s = fmaf(v, w2v[nf], s);
            }
            s += __shfl_xor(s, 1);
            s += __shfl_xor(s, 2);
            s += __shfl_xor(s, 4);
            s += __shfl_xor(s, 8);
            if (l15 == 0) {
                int e = m0 + mf * 16 + quad * 4 + r;
                if (e < E) out[e] = s + b2s;
            }
        }
    }
}

// ---- emergency fallback (tiny ws): one block per edge, fp32 vector ----
__global__ void naive_edge(const float* __restrict__ z, const int* __restrict__ eli,
                           int E, int nnodes,
                           const float* __restrict__ W1, const float* __restrict__ b1,
                           const float* __restrict__ W2, const float* __restrict__ b2,
                           float* __restrict__ out)
{
    __shared__ float red[2];
    int e = blockIdx.x;
    int j = threadIdx.x;
    int s = eli[e], d = eli[E + e];
    s = s < 0 ? 0 : (s >= nnodes ? nnodes - 1 : s);
    d = d < 0 ? 0 : (d >= nnodes ? nnodes - 1 : d);
    const float* zs = z + (long long)s * 256;
    const float* zd = z + (long long)d * 256;
    float h = b1[j];
    for (int i = 0; i < 256; ++i) h = fmaf(zs[i], W1[i * 128 + j], h);
    for (int i = 0; i < 256; ++i) h = fmaf(zd[i], W1[(256 + i) * 128 + j], h);
    h = h > 0.f ? h : 0.f;
    float v = h * W2[j];
    v += __shfl_xor(v, 1);  v += __shfl_xor(v, 2);  v += __shfl_xor(v, 4);
    v += __shfl_xor(v, 8);  v += __shfl_xor(v, 16); v += __shfl_xor(v, 32);
    if ((threadIdx.x & 63) == 0) red[threadIdx.x >> 6] = v;
    __syncthreads();
    if (threadIdx.x == 0) out[e] = red[0] + red[1] + b2[0];
}

extern "C" void kernel_launch(void* const* d_in, const int* in_sizes, int n_in,
                              void* d_out, int out_size, void* d_ws, size_t ws_size,
                              hipStream_t stream) {
    const float* z   = (const float*)d_in[0];
    const int*   eli = (const int*)d_in[1];      // int64 in reference -> int32 on device
    const float* W1  = (const float*)d_in[2];
    const float* b1  = (const float*)d_in[3];
    const float* W2  = (const float*)d_in[4];
    const float* b2  = (const float*)d_in[5];
    float*       out = (float*)d_out;

    const int E      = in_sizes[1] / 2;
    const int nnodes = in_sizes[0] / 256;

    const size_t HB   = (size_t)nnodes * 512;    // H partials fp16 [N][256]
    const size_t BT2B = 131072;                  // two-half swizzled W1 image
    const size_t BTB  = (size_t)512 * 128 * 2;   // old single image (fallback)

    const int grid_gemm = (nnodes + 127) / 128;
    const int grid_edge = (E + 63) / 64;

    if (ws_size >= HB + BT2B) {
        // primary: R11 precompute GEMM (depth-4 A prefetch) + gather edge phase
        _Float16*       Hh   = (_Float16*)d_ws;
        unsigned short* BTc2 = (unsigned short*)((char*)d_ws + HB);
        cvt_w1h<<<256, 256, 0, stream>>>(W1, BTc2);
        gemm_hb<<<grid_gemm, 256, 0, stream>>>(z, nnodes, BTc2, b1, Hh);
        edge_out<<<grid_edge, 256, 0, stream>>>(Hh, eli, E, nnodes, W2, b2, out);
    } else if (ws_size >= BTB) {
        unsigned short* BTc = (unsigned short*)d_ws;
        cvt_w1<<<256, 256, 0, stream>>>(W1, BTc);
        fused_mlp_f32<<<(E + 255) / 256, 256, 0, stream>>>(z, eli, E, nnodes, BTc, b1, W2, b2, out);
    } else {
        naive_edge<<<E, 128, 0, stream>>>(z, eli, E, nnodes, W1, b1, W2, b2, out);
    }
}